// Round 6
// baseline (394.062 us; speedup 1.0000x reference)
//
#include <hip/hip_runtime.h>
#include <stddef.h>

#define BB 32
#define NN 1024
#define HH 128

using f32x4 = __attribute__((ext_vector_type(4))) float;
using f16x8 = __attribute__((ext_vector_type(8))) _Float16;
using f16x4 = __attribute__((ext_vector_type(4))) _Float16;

// W^T in fp16, [p][n][k] = W_p[k][n]; p: 0=q, 1=k, 2=v.
__device__ _Float16 g_WT[3 * 128 * 128];

// ---------------- W transpose + cast to fp16 (tiny: 3 blocks) ----------------
__global__ __launch_bounds__(256) void wtrans_kernel(const float* __restrict__ Wq,
                                                     const float* __restrict__ Wk,
                                                     const float* __restrict__ Wv) {
    __shared__ float wl[128 * 128];
    const float* W = (blockIdx.x == 0) ? Wq : (blockIdx.x == 1) ? Wk : Wv;
    _Float16* dst = g_WT + blockIdx.x * 16384;
    const int tid = threadIdx.x;
    for (int i = tid; i < 4096; i += 256) ((f32x4*)wl)[i] = ((const f32x4*)W)[i];
    __syncthreads();
    for (int s = 0; s < 8; ++s) {
        int ch = tid + s * 256;
        int n = ch >> 4, kc = ch & 15;
        f16x8 v;
        #pragma unroll
        for (int j = 0; j < 8; ++j) v[j] = (_Float16)wl[(kc * 8 + j) * 128 + n];
        *(f16x8*)&dst[n * 128 + kc * 8] = v;
    }
}

// ---------------- Mask bit-pack: 128 MB fp32 -> 4 MB bitmask ----------------
// The ONLY kernel that reads the fp32 mask from HBM, with sequential per-wave
// streaming (each thread packs 32 consecutive floats -> one u32). Row-major
// bit layout: bm[b*N*32 + i*32 + w] bit e = (mask[b][i][w*32+e] != 0).
__global__ __launch_bounds__(256) void maskpack_kernel(const float* __restrict__ mask,
                                                       unsigned* __restrict__ bm) {
    const int gtid = blockIdx.x * 256 + threadIdx.x;
    for (int w = gtid; w < BB * NN * NN / 32; w += 262144) {
        const f32x4* src = (const f32x4*)(mask + (size_t)w * 32);
        unsigned bits = 0;
        #pragma unroll
        for (int i4 = 0; i4 < 8; ++i4) {
            f32x4 f = src[i4];
            #pragma unroll
            for (int c = 0; c < 4; ++c)
                if (f[c] != 0.0f) bits |= (1u << (i4 * 4 + c));
        }
        bm[w] = bits;
    }
}

// ---------------- Projection via MFMA ----------------
__global__ __launch_bounds__(256) void proj_kernel(
    const float* __restrict__ x,
    const float* __restrict__ bq, const float* __restrict__ bk, const float* __restrict__ bv,
    _Float16* __restrict__ qo, _Float16* __restrict__ ko, _Float16* __restrict__ vTo)
{
    __shared__ __align__(16) _Float16 rep[4][16 * 136];
    __shared__ __align__(16) _Float16 vsm[128 * 72];
    const int tid = threadIdx.x;
    const int w = tid >> 6, ln = tid & 63, qd = ln >> 4, l16 = ln & 15;
    const int row0 = blockIdx.x * 64;
    const int rw = row0 + w * 16;
    const int b = row0 >> 10, n0 = row0 & 1023;

    f16x8 xa[4];
    {
        const float* xr = x + (size_t)(rw + l16) * 128;
        #pragma unroll
        for (int t = 0; t < 4; ++t) {
            f32x4 a0 = *(const f32x4*)(xr + t * 32 + qd * 8);
            f32x4 a1 = *(const f32x4*)(xr + t * 32 + qd * 8 + 4);
            #pragma unroll
            for (int j = 0; j < 4; ++j) { xa[t][j] = (_Float16)a0[j]; xa[t][4 + j] = (_Float16)a1[j]; }
        }
    }

    for (int p = 0; p < 3; ++p) {
        const _Float16* Wt = g_WT + p * 16384;
        const float* bias = (p == 0) ? bq : (p == 1) ? bk : bv;

        float bv_[8];
        #pragma unroll
        for (int hc = 0; hc < 8; ++hc) bv_[hc] = bias[hc * 16 + l16];

        f32x4 acc[8];
        #pragma unroll
        for (int hc = 0; hc < 8; ++hc) {
            acc[hc] = (f32x4)(0.0f);
            #pragma unroll
            for (int t = 0; t < 4; ++t) {
                f16x8 bf = *(const f16x8*)(Wt + (size_t)(hc * 16 + l16) * 128 + t * 32 + qd * 8);
                acc[hc] = __builtin_amdgcn_mfma_f32_16x16x32_f16(xa[t], bf, acc[hc], 0, 0, 0);
            }
        }

        if (p < 2) {
            _Float16* dst = (p == 0) ? qo : ko;
            #pragma unroll
            for (int hc = 0; hc < 8; ++hc)
                #pragma unroll
                for (int r = 0; r < 4; ++r)
                    rep[w][(qd * 4 + r) * 136 + hc * 16 + l16] =
                        (_Float16)fmaxf(acc[hc][r] + bv_[hc], 0.0f);
            #pragma unroll
            for (int s = 0; s < 4; ++s) {
                int ch = ln + s * 64;
                int rr = ch >> 4, kc = ch & 15;
                f16x8 v = *(const f16x8*)&rep[w][rr * 136 + kc * 8];
                *(f16x8*)&dst[(size_t)(rw + rr) * 128 + kc * 8] = v;
            }
        } else {
            #pragma unroll
            for (int hc = 0; hc < 8; ++hc)
                #pragma unroll
                for (int r = 0; r < 4; ++r)
                    vsm[(hc * 16 + l16) * 72 + w * 16 + qd * 4 + r] =
                        (_Float16)fmaxf(acc[hc][r] + bv_[hc], 0.0f);
            __syncthreads();
            #pragma unroll
            for (int s = 0; s < 4; ++s) {
                int ch = tid + s * 256;
                int h = ch >> 3, g = ch & 7;
                f16x8 v = *(const f16x8*)&vsm[h * 72 + g * 8];
                *(f16x8*)&vTo[(size_t)b * HH * NN + (size_t)h * NN + n0 + g * 8] = v;
            }
        }
    }
}

// ---------------- Fused attention: S^T orientation, barrier-free, bitmask ----
// grid (32, 32). 256 thr = 4 waves; pair = w>>1 (16 i-rows), half = w&1 (512 j).
// No __syncthreads in the K-loop; only LDS use is the wave-private P round-trip.
// Mask comes from the 4 MB LLC-resident bitmask: ONE u32 per lane covers a whole
// 32-j tile (bit c*16+qd*4+r <-> s{c}[r]). All attn streams are cache-resident.
__global__ __launch_bounds__(256, 2) void attn_kernel(
    const _Float16* __restrict__ q, const _Float16* __restrict__ k,
    const _Float16* __restrict__ vT, const unsigned* __restrict__ mb,
    float* __restrict__ out)
{
    __shared__ __align__(16) unsigned char smem[17920];
    _Float16* ps = (_Float16*)smem;      // [4 waves][16 i][stride 40 f16] = 5120 B
    float* mg = (float*)smem;            // merge overlay after the loop

    const int tid = threadIdx.x;
    const int w = tid >> 6, ln = tid & 63, qd = ln >> 4, l16 = ln & 15;
    const int pair = w >> 1, half = w & 1;
    const int b = blockIdx.y;
    const int i0 = blockIdx.x * 32 + pair * 16;

    _Float16* psw = ps + w * 640;

    // Q B-fragments (n = l16 = i, k = qd*8+j)
    f16x8 qf[4];
    {
        const _Float16* qrow = q + ((size_t)b * NN + i0 + l16) * 128;
        #pragma unroll
        for (int t = 0; t < 4; ++t)
            qf[t] = *(const f16x8*)(qrow + t * 32 + qd * 8);
    }

    const _Float16* kbase = k + (size_t)b * NN * 128 + (size_t)half * 512 * 128;
    const _Float16* vbase = vT + (size_t)b * HH * NN + half * 512;
    // bit-words for this lane's row, this half: 16 words of 32 j each
    const unsigned* mbase = mb + (size_t)b * NN * 32 + (size_t)(i0 + l16) * 32 + half * 16;

    f32x4 acc[8];
    #pragma unroll
    for (int hc = 0; hc < 8; ++hc) acc[hc] = (f32x4)(0.0f);
    float m_i = -1e30f, l_i = 0.0f;    // per-lane (i = l16); m_i quad-uniform

    // preload: K A-frags tile0, mask words 0 and 1 (ring, distance 2)
    f16x8 kc[8];
    #pragma unroll
    for (int c = 0; c < 2; ++c)
        #pragma unroll
        for (int t = 0; t < 4; ++t)
            kc[c * 4 + t] = *(const f16x8*)(kbase + (size_t)(c * 16 + l16) * 128 + t * 32 + qd * 8);
    unsigned mring[2] = { mbase[0], mbase[1] };

    #pragma unroll 2
    for (int jt = 0; jt < 16; ++jt) {
        const int j0 = jt * 32;
        const int jn = (jt < 15) ? j0 + 32 : 0;   // kc reload target (wraps)
        const int wm = (jt < 14) ? jt + 2 : 0;    // mask word reload target
        const int cur = jt & 1;

        // (1) V^T A-fragments for CURRENT tile — issued first
        f16x8 vf[8];
        #pragma unroll
        for (int hc = 0; hc < 8; ++hc)
            vf[hc] = *(const f16x8*)(vbase + (size_t)(hc * 16 + l16) * NN + j0 + qd * 8);

        // (2) S^T = K·Q^T : col = i = l16, row = j = qd*4+r (+16c)
        f32x4 s0 = (f32x4)(0.0f), s1 = (f32x4)(0.0f);
        #pragma unroll
        for (int t = 0; t < 4; ++t) {
            s0 = __builtin_amdgcn_mfma_f32_16x16x32_f16(kc[t],     qf[t], s0, 0, 0, 0);
            s1 = __builtin_amdgcn_mfma_f32_16x16x32_f16(kc[4 + t], qf[t], s1, 0, 0, 0);
        }

        // (3) reload kc in place for NEXT tile (consumed by S above)
        #pragma unroll
        for (int c = 0; c < 2; ++c)
            #pragma unroll
            for (int t = 0; t < 4; ++t)
                kc[c * 4 + t] = *(const f16x8*)(kbase + (size_t)(jn + c * 16 + l16) * 128 + t * 32 + qd * 8);

        // (4) mask word + reload ring slot (distance 2)
        const unsigned wv = mring[cur];
        mring[cur] = mbase[wm];

        // (5) softmax: bit-select, 7 in-lane v_max + 2 shuffles; no sum tree
        float lg[8];
        #pragma unroll
        for (int r = 0; r < 4; ++r) {
            lg[r]     = ((wv >> (qd * 4 + r)) & 1u)      ? s0[r] : -1e30f;
            lg[4 + r] = ((wv >> (16 + qd * 4 + r)) & 1u) ? s1[r] : -1e30f;
        }
        float tmax = lg[0];
        #pragma unroll
        for (int z = 1; z < 8; ++z) tmax = fmaxf(tmax, lg[z]);
        tmax = fmaxf(tmax, __shfl_xor(tmax, 16));
        tmax = fmaxf(tmax, __shfl_xor(tmax, 32));
        float mnew = fmaxf(m_i, tmax);
        float sc = __expf(m_i - mnew);
        float p[8], rs = 0.0f;
        #pragma unroll
        for (int z = 0; z < 8; ++z) { p[z] = __expf(lg[z] - mnew); rs += p[z]; }
        l_i = l_i * sc + rs;
        m_i = mnew;

        // (6) P -> LDS (P[i=l16][j], stride 40 f16): two b64 writes
        f16x4 pk0, pk1;
        #pragma unroll
        for (int r = 0; r < 4; ++r) { pk0[r] = (_Float16)p[r]; pk1[r] = (_Float16)p[4 + r]; }
        *(f16x4*)&psw[l16 * 40 + qd * 4]      = pk0;
        *(f16x4*)&psw[l16 * 40 + 16 + qd * 4] = pk1;

        // (7) rescale accumulators (sc uniform per lane)
        #pragma unroll
        for (int hc = 0; hc < 8; ++hc) acc[hc] *= sc;

        // (8) O^T += V^T · P^T : B-frag = P[i=l16][j=qd*8..], one b128 read
        f16x8 pb = *(const f16x8*)&psw[l16 * 40 + qd * 8];
        #pragma unroll
        for (int hc = 0; hc < 8; ++hc)
            acc[hc] = __builtin_amdgcn_mfma_f32_16x16x32_f16(vf[hc], pb, acc[hc], 0, 0, 0);
    }

    // reduce l across quads (j-partition) — 2 shuffles, once
    l_i += __shfl_xor(l_i, 16);
    l_i += __shfl_xor(l_i, 32);

    // ---- merge the two j-halves (overlay on ps; stride 136 floats) ----
    __syncthreads();
    float* mgp = mg + pair * 2176;          // [16 i][136]
    float* ml  = mg + 4352;                 // [pair][{m,l}][16]
    if (half == 1) {
        #pragma unroll
        for (int hc = 0; hc < 8; ++hc)
            *(f32x4*)&mgp[l16 * 136 + hc * 16 + qd * 4] = acc[hc];
        if (qd == 0) {
            ml[pair * 32 + l16]      = m_i;
            ml[pair * 32 + 16 + l16] = l_i;
        }
    }
    __syncthreads();
    if (half == 0) {
        float m1  = ml[pair * 32 + l16];
        float l1v = ml[pair * 32 + 16 + l16];
        float M = fmaxf(m_i, m1);
        float a0 = __expf(m_i - M), a1 = __expf(m1 - M);
        float inv = 1.0f / (l_i * a0 + l1v * a1);
        a0 *= inv; a1 *= inv;
        float* orow = out + ((size_t)b * NN + i0 + l16) * 128;
        #pragma unroll
        for (int hc = 0; hc < 8; ++hc) {
            f32x4 o1 = *(const f32x4*)&mgp[l16 * 136 + hc * 16 + qd * 4];
            f32x4 o = acc[hc] * a0 + o1 * a1;
            *(f32x4*)&orow[hc * 16 + qd * 4] = o;
        }
    }
}

extern "C" void kernel_launch(void* const* d_in, const int* in_sizes, int n_in,
                              void* d_out, int out_size, void* d_ws, size_t ws_size,
                              hipStream_t stream) {
    const float* x    = (const float*)d_in[0];
    const float* mask = (const float*)d_in[1];
    const float* Wv   = (const float*)d_in[2];
    const float* bv   = (const float*)d_in[3];
    const float* Wk   = (const float*)d_in[4];
    const float* bk   = (const float*)d_in[5];
    const float* Wq   = (const float*)d_in[6];
    const float* bq   = (const float*)d_in[7];
    float* out = (float*)d_out;

    const size_t BNH = (size_t)BB * NN * HH;
    _Float16* ws  = (_Float16*)d_ws;
    _Float16* vTb = ws;                       // [B][H][N]       8 MB
    _Float16* kb  = ws + BNH;                 // [B][N][H]       8 MB
    _Float16* qb  = ws + 2 * BNH;             // [B][N][H]       8 MB
    unsigned* bmask = (unsigned*)(ws + 3 * BNH);  // [B][N][32]  4 MB

    wtrans_kernel<<<3, 256, 0, stream>>>(Wq, Wk, Wv);
    maskpack_kernel<<<1024, 256, 0, stream>>>(mask, bmask);
    proj_kernel<<<512, 256, 0, stream>>>(x, bq, bk, bv, qb, kb, vTb);
    attn_kernel<<<dim3(32, 32), 256, 0, stream>>>(qb, kb, vTb, bmask, out);
}

// Round 7
// 292.478 us; speedup vs baseline: 1.3473x; 1.3473x over previous
//
#include <hip/hip_runtime.h>
#include <stddef.h>

#define BB 32
#define NN 1024
#define HH 128

using f32x4 = __attribute__((ext_vector_type(4))) float;
using f16x8 = __attribute__((ext_vector_type(8))) _Float16;
using f16x4 = __attribute__((ext_vector_type(4))) _Float16;
typedef unsigned long long u64;

#define AS1 __attribute__((address_space(1)))
#define AS3 __attribute__((address_space(3)))

// W^T in fp16, [p][n][k] = W_p[k][n]; p: 0=q, 1=k, 2=v.
__device__ _Float16 g_WT[3 * 128 * 128];

// ---------------- W transpose + cast to fp16 (3 blocks; LDS padded to 129) ----
__global__ __launch_bounds__(256) void wtrans_kernel(const float* __restrict__ Wq,
                                                     const float* __restrict__ Wk,
                                                     const float* __restrict__ Wv) {
    __shared__ float wl[128 * 129];
    const float* W = (blockIdx.x == 0) ? Wq : (blockIdx.x == 1) ? Wk : Wv;
    _Float16* dst = g_WT + blockIdx.x * 16384;
    const int tid = threadIdx.x;
    for (int i = tid; i < 4096; i += 256) {
        int row = i >> 5, c = i & 31;
        *(f32x4*)&wl[row * 129 + c * 4] = ((const f32x4*)W)[i];
    }
    __syncthreads();
    for (int s = 0; s < 8; ++s) {
        int ch = tid + s * 256;
        int n = ch >> 4, kc = ch & 15;
        f16x8 v;
        #pragma unroll
        for (int j = 0; j < 8; ++j) v[j] = (_Float16)wl[(kc * 8 + j) * 129 + n];
        *(f16x8*)&dst[n * 128 + kc * 8] = v;
    }
}

// ---------------- Mask pack via ballot: 128 MB fp32 -> 4 MB bit words --------
// chunk ch covers 256 consecutive floats. Lane l reads f32x4 at ch*256+l*4
// (wave reads 1 KB fully coalesced). Ballot c: bit l <-> element l*4+c.
// Output: bm[ch*4 + c] = ballot_c.
__global__ __launch_bounds__(256) void maskpack_kernel(const float* __restrict__ mask,
                                                       u64* __restrict__ bm) {
    const int wid = (blockIdx.x * 256 + threadIdx.x) >> 6;
    const int ln = threadIdx.x & 63;
    const int nw = gridDim.x * 4;
    for (int ch = wid; ch < BB * NN * NN / 256; ch += nw) {
        f32x4 f = *(const f32x4*)(mask + (size_t)ch * 256 + ln * 4);
        u64 b0 = __ballot(f[0] != 0.0f);
        u64 b1 = __ballot(f[1] != 0.0f);
        u64 b2 = __ballot(f[2] != 0.0f);
        u64 b3 = __ballot(f[3] != 0.0f);
        if (ln == 0) {
            bm[(size_t)ch * 4 + 0] = b0;
            bm[(size_t)ch * 4 + 1] = b1;
            bm[(size_t)ch * 4 + 2] = b2;
            bm[(size_t)ch * 4 + 3] = b3;
        }
    }
}

// ---------------- Projection via MFMA (unchanged, passing since R3) ----------
__global__ __launch_bounds__(256) void proj_kernel(
    const float* __restrict__ x,
    const float* __restrict__ bq, const float* __restrict__ bk, const float* __restrict__ bv,
    _Float16* __restrict__ qo, _Float16* __restrict__ ko, _Float16* __restrict__ vTo)
{
    __shared__ __align__(16) _Float16 rep[4][16 * 136];
    __shared__ __align__(16) _Float16 vsm[128 * 72];
    const int tid = threadIdx.x;
    const int w = tid >> 6, ln = tid & 63, qd = ln >> 4, l16 = ln & 15;
    const int row0 = blockIdx.x * 64;
    const int rw = row0 + w * 16;
    const int b = row0 >> 10, n0 = row0 & 1023;

    f16x8 xa[4];
    {
        const float* xr = x + (size_t)(rw + l16) * 128;
        #pragma unroll
        for (int t = 0; t < 4; ++t) {
            f32x4 a0 = *(const f32x4*)(xr + t * 32 + qd * 8);
            f32x4 a1 = *(const f32x4*)(xr + t * 32 + qd * 8 + 4);
            #pragma unroll
            for (int j = 0; j < 4; ++j) { xa[t][j] = (_Float16)a0[j]; xa[t][4 + j] = (_Float16)a1[j]; }
        }
    }

    for (int p = 0; p < 3; ++p) {
        const _Float16* Wt = g_WT + p * 16384;
        const float* bias = (p == 0) ? bq : (p == 1) ? bk : bv;

        float bv_[8];
        #pragma unroll
        for (int hc = 0; hc < 8; ++hc) bv_[hc] = bias[hc * 16 + l16];

        f32x4 acc[8];
        #pragma unroll
        for (int hc = 0; hc < 8; ++hc) {
            acc[hc] = (f32x4)(0.0f);
            #pragma unroll
            for (int t = 0; t < 4; ++t) {
                f16x8 bf = *(const f16x8*)(Wt + (size_t)(hc * 16 + l16) * 128 + t * 32 + qd * 8);
                acc[hc] = __builtin_amdgcn_mfma_f32_16x16x32_f16(xa[t], bf, acc[hc], 0, 0, 0);
            }
        }

        if (p < 2) {
            _Float16* dst = (p == 0) ? qo : ko;
            #pragma unroll
            for (int hc = 0; hc < 8; ++hc)
                #pragma unroll
                for (int r = 0; r < 4; ++r)
                    rep[w][(qd * 4 + r) * 136 + hc * 16 + l16] =
                        (_Float16)fmaxf(acc[hc][r] + bv_[hc], 0.0f);
            #pragma unroll
            for (int s = 0; s < 4; ++s) {
                int ch = ln + s * 64;
                int rr = ch >> 4, kc = ch & 15;
                f16x8 v = *(const f16x8*)&rep[w][rr * 136 + kc * 8];
                *(f16x8*)&dst[(size_t)(rw + rr) * 128 + kc * 8] = v;
            }
        } else {
            #pragma unroll
            for (int hc = 0; hc < 8; ++hc)
                #pragma unroll
                for (int r = 0; r < 4; ++r)
                    vsm[(hc * 16 + l16) * 72 + w * 16 + qd * 4 + r] =
                        (_Float16)fmaxf(acc[hc][r] + bv_[hc], 0.0f);
            __syncthreads();
            #pragma unroll
            for (int s = 0; s < 4; ++s) {
                int ch = tid + s * 256;
                int h = ch >> 3, g = ch & 7;
                f16x8 v = *(const f16x8*)&vsm[h * 72 + g * 8];
                *(f16x8*)&vTo[(size_t)b * HH * NN + (size_t)h * NN + n0 + g * 8] = v;
            }
        }
    }
}

// ---------------- Fused attention: m97-style DMA-staged, S^T, XCD-pinned -----
// grid 1024 (1D): b = id&31 (XCD = b%8 -> per-batch K/V/q L2-resident),
// ib = id>>5. Block: 32 i-rows; 4 waves: pair=w>>1 (16 rows), half=w&1 (512 j).
// Per j-tile (32): stage K(2x8KB)+V(2x8KB) via global_load_lds width16 (DMA,
// un-sinkable, no VGPR roundtrip); XOR-swizzled LDS (no padding allowed):
//   K: row r chunk c at slot c^(r&15); V: row h chunk c at slot c^(h&3).
// Mask: 4 u64 bit-words per lane reloaded once per 8 tiles.
__global__ __launch_bounds__(256, 4) void attn_kernel(
    const _Float16* __restrict__ q, const _Float16* __restrict__ k,
    const _Float16* __restrict__ vT, const u64* __restrict__ bm,
    float* __restrict__ out)
{
    __shared__ __align__(16) unsigned char smem[37888];
    _Float16* ks = (_Float16*)smem;                  // [2 halves][8192 B] swizzled
    _Float16* vs = (_Float16*)(smem + 16384);        // [2 halves][8192 B] swizzled
    _Float16* ps = (_Float16*)(smem + 32768);        // [4 waves][16*40] = 5120 B
    float* mg = (float*)smem;                        // merge overlay after loop

    const int tid = threadIdx.x;
    const int w = tid >> 6, ln = tid & 63, qd = ln >> 4, l16 = ln & 15;
    const int pair = w >> 1, half = w & 1;
    const int b = blockIdx.x & 31, ib = blockIdx.x >> 5;
    const int i0 = ib * 32 + pair * 16;

    _Float16* psw = ps + w * 640;

    // Q B-fragments (n = l16 = i, k = qd*8+j)
    f16x8 qf[4];
    {
        const _Float16* qrow = q + ((size_t)b * NN + i0 + l16) * 128;
        #pragma unroll
        for (int t = 0; t < 4; ++t)
            qf[t] = *(const f16x8*)(qrow + t * 32 + qd * 8);
    }

    f32x4 acc[8];
    #pragma unroll
    for (int hc = 0; hc < 8; ++hc) acc[hc] = (f32x4)(0.0f);
    float m_i = -1e30f, l_i = 0.0f;

    u64 mw[4];
    // bit-words base for this lane's i-row: index ((b*N+i)*4 + s)*4
    const u64* mwp = bm + ((size_t)b * NN + i0 + l16) * 16;

    for (int jt = 0; jt < 16; ++jt) {
        __syncthreads();                      // previous compute done with LDS
        // ---- stage tile jt via DMA (wave roles: 0,1 -> K halves; 2,3 -> V) ----
        if (w < 2) {
            const _Float16* kg = k + ((size_t)b * NN + w * 512 + jt * 32) * 128;
            unsigned char* ldsb = smem + w * 8192;
            #pragma unroll
            for (int g = 0; g < 8; ++g) {
                int r  = g * 4 + (ln >> 4);
                int cs = (ln & 15) ^ (r & 15);
                __builtin_amdgcn_global_load_lds(
                    (const AS1 void*)(kg + (size_t)r * 128 + cs * 8),
                    (AS3 void*)(ldsb + g * 1024 + (ln & 15) * 16),
                    16, 0, 0);
            }
        } else {
            const int vh = w - 2;
            const _Float16* vg = vT + (size_t)b * HH * NN + vh * 512 + jt * 32;
            unsigned char* ldsb = smem + 16384 + vh * 8192;
            #pragma unroll
            for (int g = 0; g < 8; ++g) {
                int h  = g * 16 + (ln >> 2);
                int cs = (ln & 3) ^ (h & 3);
                __builtin_amdgcn_global_load_lds(
                    (const AS1 void*)(vg + (size_t)h * NN + cs * 8),
                    (AS3 void*)(ldsb + g * 1024 + (ln & 3) * 16),
                    16, 0, 0);
            }
        }
        // mask words: once per 8 tiles (4 u64 = bits for 256 j)
        if ((jt & 7) == 0) {
            const u64* mp = mwp + (half * 2 + (jt >> 3)) * 4;
            mw[0] = mp[0]; mw[1] = mp[1]; mw[2] = mp[2]; mw[3] = mp[3];
        }
        __syncthreads();                      // vmcnt(0) drain: DMA complete

        // ---- compute ----
        const _Float16* ksh = ks + half * 4096;   // f16 units
        const _Float16* vsh = vs + half * 4096;

        f32x4 s0 = (f32x4)(0.0f), s1 = (f32x4)(0.0f);
        #pragma unroll
        for (int t = 0; t < 4; ++t) {
            f16x8 kc = *(const f16x8*)&ksh[l16 * 128 + (((t * 4 + qd) ^ l16) * 8)];
            s0 = __builtin_amdgcn_mfma_f32_16x16x32_f16(kc, qf[t], s0, 0, 0, 0);
        }
        #pragma unroll
        for (int t = 0; t < 4; ++t) {
            f16x8 kc = *(const f16x8*)&ksh[(16 + l16) * 128 + (((t * 4 + qd) ^ l16) * 8)];
            s1 = __builtin_amdgcn_mfma_f32_16x16x32_f16(kc, qf[t], s1, 0, 0, 0);
        }

        // softmax: bits from mw (word r, bit B4 + c16*4 + qd)
        const int sh0 = (jt & 7) * 8 + qd, sh1 = sh0 + 4;
        float lg[8];
        #pragma unroll
        for (int r = 0; r < 4; ++r) {
            lg[r]     = ((mw[r] >> sh0) & 1ull) ? s0[r] : -1e30f;
            lg[4 + r] = ((mw[r] >> sh1) & 1ull) ? s1[r] : -1e30f;
        }
        float tmax = lg[0];
        #pragma unroll
        for (int z = 1; z < 8; ++z) tmax = fmaxf(tmax, lg[z]);
        tmax = fmaxf(tmax, __shfl_xor(tmax, 16));
        tmax = fmaxf(tmax, __shfl_xor(tmax, 32));
        float mnew = fmaxf(m_i, tmax);
        float sc = __expf(m_i - mnew);
        float p[8], rs = 0.0f;
        #pragma unroll
        for (int z = 0; z < 8; ++z) { p[z] = __expf(lg[z] - mnew); rs += p[z]; }
        l_i = l_i * sc + rs;
        m_i = mnew;

        // P -> LDS (wave-private; stride 40 f16)
        f16x4 pk0, pk1;
        #pragma unroll
        for (int r = 0; r < 4; ++r) { pk0[r] = (_Float16)p[r]; pk1[r] = (_Float16)p[4 + r]; }
        *(f16x4*)&psw[l16 * 40 + qd * 4]      = pk0;
        *(f16x4*)&psw[l16 * 40 + 16 + qd * 4] = pk1;

        #pragma unroll
        for (int hc = 0; hc < 8; ++hc) acc[hc] *= sc;

        f16x8 pb = *(const f16x8*)&psw[l16 * 40 + qd * 8];
        #pragma unroll
        for (int hc = 0; hc < 8; ++hc) {
            f16x8 vf = *(const f16x8*)&vsh[(hc * 16 + l16) * 32 + ((qd ^ (l16 & 3)) * 8)];
            acc[hc] = __builtin_amdgcn_mfma_f32_16x16x32_f16(vf, pb, acc[hc], 0, 0, 0);
        }
    }

    // reduce l across quads (j-partition within half)
    l_i += __shfl_xor(l_i, 16);
    l_i += __shfl_xor(l_i, 32);

    // ---- merge the two j-halves (overlay on smem) ----
    __syncthreads();
    float* mgp = mg + pair * 2176;          // [16 i][136]
    float* ml  = mg + 4352;                 // [pair][{m,l}][16]
    if (half == 1) {
        #pragma unroll
        for (int hc = 0; hc < 8; ++hc)
            *(f32x4*)&mgp[l16 * 136 + hc * 16 + qd * 4] = acc[hc];
        if (qd == 0) {
            ml[pair * 32 + l16]      = m_i;
            ml[pair * 32 + 16 + l16] = l_i;
        }
    }
    __syncthreads();
    if (half == 0) {
        float m1  = ml[pair * 32 + l16];
        float l1v = ml[pair * 32 + 16 + l16];
        float M = fmaxf(m_i, m1);
        float a0 = __expf(m_i - M), a1 = __expf(m1 - M);
        float inv = 1.0f / (l_i * a0 + l1v * a1);
        a0 *= inv; a1 *= inv;
        float* orow = out + ((size_t)b * NN + i0 + l16) * 128;
        #pragma unroll
        for (int hc = 0; hc < 8; ++hc) {
            f32x4 o1 = *(const f32x4*)&mgp[l16 * 136 + hc * 16 + qd * 4];
            f32x4 o = acc[hc] * a0 + o1 * a1;
            *(f32x4*)&orow[hc * 16 + qd * 4] = o;
        }
    }
}

extern "C" void kernel_launch(void* const* d_in, const int* in_sizes, int n_in,
                              void* d_out, int out_size, void* d_ws, size_t ws_size,
                              hipStream_t stream) {
    const float* x    = (const float*)d_in[0];
    const float* mask = (const float*)d_in[1];
    const float* Wv   = (const float*)d_in[2];
    const float* bv   = (const float*)d_in[3];
    const float* Wk   = (const float*)d_in[4];
    const float* bk   = (const float*)d_in[5];
    const float* Wq   = (const float*)d_in[6];
    const float* bq   = (const float*)d_in[7];
    float* out = (float*)d_out;

    const size_t BNH = (size_t)BB * NN * HH;
    _Float16* ws  = (_Float16*)d_ws;
    _Float16* vTb = ws;                       // [B][H][N]   8 MB
    _Float16* kb  = ws + BNH;                 // [B][N][H]   8 MB
    _Float16* qb  = ws + 2 * BNH;             // [B][N][H]   8 MB
    u64* bm64 = (u64*)(ws + 3 * BNH);         // 4 MB bit words

    wtrans_kernel<<<3, 256, 0, stream>>>(Wq, Wk, Wv);
    maskpack_kernel<<<1024, 256, 0, stream>>>(mask, bm64);
    proj_kernel<<<512, 256, 0, stream>>>(x, bq, bk, bv, qb, kb, vTb);
    attn_kernel<<<1024, 256, 0, stream>>>(qb, kb, vTb, bm64, out);
}

// Round 8
// 289.534 us; speedup vs baseline: 1.3610x; 1.0102x over previous
//
#include <hip/hip_runtime.h>
#include <stddef.h>

#define BB 32
#define NN 1024
#define HH 128

using f32x4 = __attribute__((ext_vector_type(4))) float;
using f16x8 = __attribute__((ext_vector_type(8))) _Float16;
using f16x4 = __attribute__((ext_vector_type(4))) _Float16;
typedef unsigned long long u64;

#define AS1 __attribute__((address_space(1)))
#define AS3 __attribute__((address_space(3)))

// W^T in fp16, [p][n][k] = W_p[k][n]; p: 0=q, 1=k, 2=v.
__device__ _Float16 g_WT[3 * 128 * 128];

// ---------------- W transpose + cast to fp16 (3 blocks; LDS padded to 129) ----
__global__ __launch_bounds__(256) void wtrans_kernel(const float* __restrict__ Wq,
                                                     const float* __restrict__ Wk,
                                                     const float* __restrict__ Wv) {
    __shared__ float wl[128 * 129];
    const float* W = (blockIdx.x == 0) ? Wq : (blockIdx.x == 1) ? Wk : Wv;
    _Float16* dst = g_WT + blockIdx.x * 16384;
    const int tid = threadIdx.x;
    for (int i = tid; i < 4096; i += 256) {
        int row = i >> 5, c = i & 31;
        *(f32x4*)&wl[row * 129 + c * 4] = ((const f32x4*)W)[i];
    }
    __syncthreads();
    for (int s = 0; s < 8; ++s) {
        int ch = tid + s * 256;
        int n = ch >> 4, kc = ch & 15;
        f16x8 v;
        #pragma unroll
        for (int j = 0; j < 8; ++j) v[j] = (_Float16)wl[(kc * 8 + j) * 129 + n];
        *(f16x8*)&dst[n * 128 + kc * 8] = v;
    }
}

// ---------------- Mask pack via ballot: 128 MB fp32 -> 4 MB bit words --------
__global__ __launch_bounds__(256) void maskpack_kernel(const float* __restrict__ mask,
                                                       u64* __restrict__ bm) {
    const int wid = (blockIdx.x * 256 + threadIdx.x) >> 6;
    const int ln = threadIdx.x & 63;
    const int nw = gridDim.x * 4;
    for (int ch = wid; ch < BB * NN * NN / 256; ch += nw) {
        f32x4 f = *(const f32x4*)(mask + (size_t)ch * 256 + ln * 4);
        u64 b0 = __ballot(f[0] != 0.0f);
        u64 b1 = __ballot(f[1] != 0.0f);
        u64 b2 = __ballot(f[2] != 0.0f);
        u64 b3 = __ballot(f[3] != 0.0f);
        if (ln == 0) {
            bm[(size_t)ch * 4 + 0] = b0;
            bm[(size_t)ch * 4 + 1] = b1;
            bm[(size_t)ch * 4 + 2] = b2;
            bm[(size_t)ch * 4 + 3] = b3;
        }
    }
}

// ---------------- Projection via MFMA (unchanged, passing since R3) ----------
__global__ __launch_bounds__(256) void proj_kernel(
    const float* __restrict__ x,
    const float* __restrict__ bq, const float* __restrict__ bk, const float* __restrict__ bv,
    _Float16* __restrict__ qo, _Float16* __restrict__ ko, _Float16* __restrict__ vTo)
{
    __shared__ __align__(16) _Float16 rep[4][16 * 136];
    __shared__ __align__(16) _Float16 vsm[128 * 72];
    const int tid = threadIdx.x;
    const int w = tid >> 6, ln = tid & 63, qd = ln >> 4, l16 = ln & 15;
    const int row0 = blockIdx.x * 64;
    const int rw = row0 + w * 16;
    const int b = row0 >> 10, n0 = row0 & 1023;

    f16x8 xa[4];
    {
        const float* xr = x + (size_t)(rw + l16) * 128;
        #pragma unroll
        for (int t = 0; t < 4; ++t) {
            f32x4 a0 = *(const f32x4*)(xr + t * 32 + qd * 8);
            f32x4 a1 = *(const f32x4*)(xr + t * 32 + qd * 8 + 4);
            #pragma unroll
            for (int j = 0; j < 4; ++j) { xa[t][j] = (_Float16)a0[j]; xa[t][4 + j] = (_Float16)a1[j]; }
        }
    }

    for (int p = 0; p < 3; ++p) {
        const _Float16* Wt = g_WT + p * 16384;
        const float* bias = (p == 0) ? bq : (p == 1) ? bk : bv;

        float bv_[8];
        #pragma unroll
        for (int hc = 0; hc < 8; ++hc) bv_[hc] = bias[hc * 16 + l16];

        f32x4 acc[8];
        #pragma unroll
        for (int hc = 0; hc < 8; ++hc) {
            acc[hc] = (f32x4)(0.0f);
            #pragma unroll
            for (int t = 0; t < 4; ++t) {
                f16x8 bf = *(const f16x8*)(Wt + (size_t)(hc * 16 + l16) * 128 + t * 32 + qd * 8);
                acc[hc] = __builtin_amdgcn_mfma_f32_16x16x32_f16(xa[t], bf, acc[hc], 0, 0, 0);
            }
        }

        if (p < 2) {
            _Float16* dst = (p == 0) ? qo : ko;
            #pragma unroll
            for (int hc = 0; hc < 8; ++hc)
                #pragma unroll
                for (int r = 0; r < 4; ++r)
                    rep[w][(qd * 4 + r) * 136 + hc * 16 + l16] =
                        (_Float16)fmaxf(acc[hc][r] + bv_[hc], 0.0f);
            #pragma unroll
            for (int s = 0; s < 4; ++s) {
                int ch = ln + s * 64;
                int rr = ch >> 4, kc = ch & 15;
                f16x8 v = *(const f16x8*)&rep[w][rr * 136 + kc * 8];
                *(f16x8*)&dst[(size_t)(rw + rr) * 128 + kc * 8] = v;
            }
        } else {
            #pragma unroll
            for (int hc = 0; hc < 8; ++hc)
                #pragma unroll
                for (int r = 0; r < 4; ++r)
                    vsm[(hc * 16 + l16) * 72 + w * 16 + qd * 4 + r] =
                        (_Float16)fmaxf(acc[hc][r] + bv_[hc], 0.0f);
            __syncthreads();
            #pragma unroll
            for (int s = 0; s < 4; ++s) {
                int ch = tid + s * 256;
                int h = ch >> 3, g = ch & 7;
                f16x8 v = *(const f16x8*)&vsm[h * 72 + g * 8];
                *(f16x8*)&vTo[(size_t)b * HH * NN + (size_t)h * NN + n0 + g * 8] = v;
            }
        }
    }
}

// ---------------- Fused attention: DMA-staged, S^T, 64-i blocks --------------
// grid 512 (1D): b = id&31 (XCD pin), ig = id>>5. Block: 64 i-rows, 512 thr =
// 8 waves: pair = w>>1 (16 rows), half = w&1 (512 j). Same 32 KB K/V tile now
// feeds 2x the compute vs R7 (staging amortized; barriers per FLOP halved).
// Staging roles: waves 0-3 -> K (half=w>>1, 4 groups each), 4-7 -> V.
// XOR-swizzled LDS (layout identical to R7, verified): K slot c^(r&15),
// V slot c^(h&3). Mask: 4 u64 per lane per 8 tiles.
__global__ __launch_bounds__(512, 4) void attn_kernel(
    const _Float16* __restrict__ q, const _Float16* __restrict__ k,
    const _Float16* __restrict__ vT, const u64* __restrict__ bm,
    float* __restrict__ out)
{
    __shared__ __align__(16) unsigned char smem[43008];
    _Float16* ks = (_Float16*)smem;                  // [2 halves][8192 B] swizzled
    _Float16* vs = (_Float16*)(smem + 16384);        // [2 halves][8192 B] swizzled
    _Float16* ps = (_Float16*)(smem + 32768);        // [8 waves][16*40] = 10240 B
    float* mg = (float*)smem;                        // merge overlay after loop

    const int tid = threadIdx.x;
    const int w = tid >> 6, ln = tid & 63, qd = ln >> 4, l16 = ln & 15;
    const int pair = w >> 1, half = w & 1;
    const int b = blockIdx.x & 31, ig = blockIdx.x >> 5;
    const int i0 = ig * 64 + pair * 16;

    _Float16* psw = ps + w * 640;

    // Q B-fragments (n = l16 = i, k = qd*8+j)
    f16x8 qf[4];
    {
        const _Float16* qrow = q + ((size_t)b * NN + i0 + l16) * 128;
        #pragma unroll
        for (int t = 0; t < 4; ++t)
            qf[t] = *(const f16x8*)(qrow + t * 32 + qd * 8);
    }

    f32x4 acc[8];
    #pragma unroll
    for (int hc = 0; hc < 8; ++hc) acc[hc] = (f32x4)(0.0f);
    float m_i = -1e30f, l_i = 0.0f;

    u64 mw[4];
    const u64* mwp = bm + ((size_t)b * NN + i0 + l16) * 16;

    for (int jt = 0; jt < 16; ++jt) {
        __syncthreads();                      // previous compute done with LDS
        // ---- stage tile jt via DMA: waves 0-3 K, waves 4-7 V; 4x1KB each ----
        if (w < 4) {
            const int kh = w >> 1, gb = (w & 1) * 4;
            const _Float16* kg = k + ((size_t)b * NN + kh * 512 + jt * 32) * 128;
            unsigned char* ldsb = smem + kh * 8192;
            #pragma unroll
            for (int gi = 0; gi < 4; ++gi) {
                int g  = gb + gi;
                int r  = g * 4 + (ln >> 4);
                int cs = (ln & 15) ^ (r & 15);
                __builtin_amdgcn_global_load_lds(
                    (const AS1 void*)(kg + (size_t)r * 128 + cs * 8),
                    (AS3 void*)(ldsb + g * 1024 + (ln & 15) * 16),
                    16, 0, 0);
            }
        } else {
            const int vw = w - 4;
            const int vh = vw >> 1, gb = (vw & 1) * 4;
            const _Float16* vg = vT + (size_t)b * HH * NN + vh * 512 + jt * 32;
            unsigned char* ldsb = smem + 16384 + vh * 8192;
            #pragma unroll
            for (int gi = 0; gi < 4; ++gi) {
                int g  = gb + gi;
                int h  = g * 16 + (ln >> 2);
                int cs = (ln & 3) ^ (h & 3);
                __builtin_amdgcn_global_load_lds(
                    (const AS1 void*)(vg + (size_t)h * NN + cs * 8),
                    (AS3 void*)(ldsb + g * 1024 + (ln & 3) * 16),
                    16, 0, 0);
            }
        }
        // mask words: once per 8 tiles (4 u64 = bits for 256 j)
        if ((jt & 7) == 0) {
            const u64* mp = mwp + (half * 2 + (jt >> 3)) * 4;
            mw[0] = mp[0]; mw[1] = mp[1]; mw[2] = mp[2]; mw[3] = mp[3];
        }
        __syncthreads();                      // DMA complete (vmcnt drain)

        // ---- compute ----
        const _Float16* ksh = ks + half * 4096;   // f16 units
        const _Float16* vsh = vs + half * 4096;

        f32x4 s0 = (f32x4)(0.0f), s1 = (f32x4)(0.0f);
        #pragma unroll
        for (int t = 0; t < 4; ++t) {
            f16x8 kc = *(const f16x8*)&ksh[l16 * 128 + (((t * 4 + qd) ^ l16) * 8)];
            s0 = __builtin_amdgcn_mfma_f32_16x16x32_f16(kc, qf[t], s0, 0, 0, 0);
        }
        #pragma unroll
        for (int t = 0; t < 4; ++t) {
            f16x8 kc = *(const f16x8*)&ksh[(16 + l16) * 128 + (((t * 4 + qd) ^ l16) * 8)];
            s1 = __builtin_amdgcn_mfma_f32_16x16x32_f16(kc, qf[t], s1, 0, 0, 0);
        }

        // softmax (bits: word r, lane-bit (jt&7)*8 + qd [+4 for s1])
        const int sh0 = (jt & 7) * 8 + qd, sh1 = sh0 + 4;
        float lg[8];
        #pragma unroll
        for (int r = 0; r < 4; ++r) {
            lg[r]     = ((mw[r] >> sh0) & 1ull) ? s0[r] : -1e30f;
            lg[4 + r] = ((mw[r] >> sh1) & 1ull) ? s1[r] : -1e30f;
        }
        float tmax = lg[0];
        #pragma unroll
        for (int z = 1; z < 8; ++z) tmax = fmaxf(tmax, lg[z]);
        tmax = fmaxf(tmax, __shfl_xor(tmax, 16));
        tmax = fmaxf(tmax, __shfl_xor(tmax, 32));
        float mnew = fmaxf(m_i, tmax);
        float sc = __expf(m_i - mnew);
        float p[8], rs = 0.0f;
        #pragma unroll
        for (int z = 0; z < 8; ++z) { p[z] = __expf(lg[z] - mnew); rs += p[z]; }
        l_i = l_i * sc + rs;
        m_i = mnew;

        // P -> LDS (wave-private; stride 40 f16)
        f16x4 pk0, pk1;
        #pragma unroll
        for (int r = 0; r < 4; ++r) { pk0[r] = (_Float16)p[r]; pk1[r] = (_Float16)p[4 + r]; }
        *(f16x4*)&psw[l16 * 40 + qd * 4]      = pk0;
        *(f16x4*)&psw[l16 * 40 + 16 + qd * 4] = pk1;

        #pragma unroll
        for (int hc = 0; hc < 8; ++hc) acc[hc] *= sc;

        f16x8 pb = *(const f16x8*)&psw[l16 * 40 + qd * 8];
        #pragma unroll
        for (int hc = 0; hc < 8; ++hc) {
            f16x8 vf = *(const f16x8*)&vsh[(hc * 16 + l16) * 32 + ((qd ^ (l16 & 3)) * 8)];
            acc[hc] = __builtin_amdgcn_mfma_f32_16x16x32_f16(vf, pb, acc[hc], 0, 0, 0);
        }
    }

    // reduce l across quads (j-partition within half)
    l_i += __shfl_xor(l_i, 16);
    l_i += __shfl_xor(l_i, 32);

    // ---- merge the two j-halves (overlay on smem) ----
    __syncthreads();
    float* mgp = mg + pair * 2176;          // [16 i][136] per pair (4 pairs)
    float* ml  = mg + 8704;                 // [pair][{m,l}][16]
    if (half == 1) {
        #pragma unroll
        for (int hc = 0; hc < 8; ++hc)
            *(f32x4*)&mgp[l16 * 136 + hc * 16 + qd * 4] = acc[hc];
        if (qd == 0) {
            ml[pair * 32 + l16]      = m_i;
            ml[pair * 32 + 16 + l16] = l_i;
        }
    }
    __syncthreads();
    if (half == 0) {
        float m1  = ml[pair * 32 + l16];
        float l1v = ml[pair * 32 + 16 + l16];
        float M = fmaxf(m_i, m1);
        float a0 = __expf(m_i - M), a1 = __expf(m1 - M);
        float inv = 1.0f / (l_i * a0 + l1v * a1);
        a0 *= inv; a1 *= inv;
        float* orow = out + ((size_t)b * NN + i0 + l16) * 128;
        #pragma unroll
        for (int hc = 0; hc < 8; ++hc) {
            f32x4 o1 = *(const f32x4*)&mgp[l16 * 136 + hc * 16 + qd * 4];
            f32x4 o = acc[hc] * a0 + o1 * a1;
            *(f32x4*)&orow[hc * 16 + qd * 4] = o;
        }
    }
}

extern "C" void kernel_launch(void* const* d_in, const int* in_sizes, int n_in,
                              void* d_out, int out_size, void* d_ws, size_t ws_size,
                              hipStream_t stream) {
    const float* x    = (const float*)d_in[0];
    const float* mask = (const float*)d_in[1];
    const float* Wv   = (const float*)d_in[2];
    const float* bv   = (const float*)d_in[3];
    const float* Wk   = (const float*)d_in[4];
    const float* bk   = (const float*)d_in[5];
    const float* Wq   = (const float*)d_in[6];
    const float* bq   = (const float*)d_in[7];
    float* out = (float*)d_out;

    const size_t BNH = (size_t)BB * NN * HH;
    _Float16* ws  = (_Float16*)d_ws;
    _Float16* vTb = ws;                       // [B][H][N]   8 MB
    _Float16* kb  = ws + BNH;                 // [B][N][H]   8 MB
    _Float16* qb  = ws + 2 * BNH;             // [B][N][H]   8 MB
    u64* bm64 = (u64*)(ws + 3 * BNH);         // 4 MB bit words

    wtrans_kernel<<<3, 256, 0, stream>>>(Wq, Wk, Wv);
    maskpack_kernel<<<1024, 256, 0, stream>>>(mask, bm64);
    proj_kernel<<<512, 256, 0, stream>>>(x, bq, bk, bv, qb, kb, vTb);
    attn_kernel<<<512, 512, 0, stream>>>(qb, kb, vTb, bm64, out);
}

// Round 9
// 270.489 us; speedup vs baseline: 1.4568x; 1.0704x over previous
//
#include <hip/hip_runtime.h>
#include <hip/hip_bf16.h>
#include <stddef.h>

#define BB 32
#define NN 1024
#define HH 128

using f32x4 = __attribute__((ext_vector_type(4))) float;
using f16x8 = __attribute__((ext_vector_type(8))) _Float16;
using f16x4 = __attribute__((ext_vector_type(4))) _Float16;
using s16x8 = __attribute__((ext_vector_type(8))) short;
using u16x4 = __attribute__((ext_vector_type(4))) unsigned short;
using u16x8 = __attribute__((ext_vector_type(8))) unsigned short;
typedef unsigned long long u64;
typedef unsigned short ushort;

#define AS1 __attribute__((address_space(1)))
#define AS3 __attribute__((address_space(3)))
#define LOG2E 1.44269504f

static __device__ inline ushort f2bf(float f) {
    __hip_bfloat16 h = __float2bfloat16(f);   // RNE
    return __builtin_bit_cast(ushort, h);
}

// W^T in fp16, [p][n][k] = W_p[k][n]; p: 0=q, 1=k, 2=v.
__device__ _Float16 g_WT[3 * 128 * 128];

// ---------------- W transpose + cast to fp16 (3 blocks; LDS padded to 129) ----
__global__ __launch_bounds__(256) void wtrans_kernel(const float* __restrict__ Wq,
                                                     const float* __restrict__ Wk,
                                                     const float* __restrict__ Wv) {
    __shared__ float wl[128 * 129];
    const float* W = (blockIdx.x == 0) ? Wq : (blockIdx.x == 1) ? Wk : Wv;
    _Float16* dst = g_WT + blockIdx.x * 16384;
    const int tid = threadIdx.x;
    for (int i = tid; i < 4096; i += 256) {
        int row = i >> 5, c = i & 31;
        *(f32x4*)&wl[row * 129 + c * 4] = ((const f32x4*)W)[i];
    }
    __syncthreads();
    for (int s = 0; s < 8; ++s) {
        int ch = tid + s * 256;
        int n = ch >> 4, kc = ch & 15;
        f16x8 v;
        #pragma unroll
        for (int j = 0; j < 8; ++j) v[j] = (_Float16)wl[(kc * 8 + j) * 129 + n];
        *(f16x8*)&dst[n * 128 + kc * 8] = v;
    }
}

// ---------------- Fused prep: proj (blocks 0-511) + maskpack (512-1535) ------
// Roles are independent readers -> run concurrently across CUs, overlapping
// proj's MFMA with maskpack's 128 MB HBM stream.
// proj: q = relu(xWq+bq)*LOG2E (f16)  [exp2-domain fold], k = relu(.) (f16),
//       vT = relu(.) (bf16, [B][H][N]).
// maskpack: 128 MB fp32 mask -> 4 MB bit-words via ballot (sequential stream).
__global__ __launch_bounds__(256) void prep_kernel(
    const float* __restrict__ x,
    const float* __restrict__ bq, const float* __restrict__ bk, const float* __restrict__ bv,
    const float* __restrict__ mask,
    _Float16* __restrict__ qo, _Float16* __restrict__ ko, ushort* __restrict__ vTo,
    u64* __restrict__ bm)
{
    __shared__ __align__(16) _Float16 rep[4][16 * 136];
    __shared__ __align__(16) ushort vsm[128 * 72];

    if (blockIdx.x >= 512) {
        // ---- maskpack role ----
        const int wid = ((blockIdx.x - 512) * 256 + threadIdx.x) >> 6;
        const int ln = threadIdx.x & 63;
        for (int ch = wid; ch < BB * NN * NN / 256; ch += 4096) {
            f32x4 f = *(const f32x4*)(mask + (size_t)ch * 256 + ln * 4);
            u64 b0 = __ballot(f[0] != 0.0f);
            u64 b1 = __ballot(f[1] != 0.0f);
            u64 b2 = __ballot(f[2] != 0.0f);
            u64 b3 = __ballot(f[3] != 0.0f);
            if (ln == 0) {
                bm[(size_t)ch * 4 + 0] = b0;
                bm[(size_t)ch * 4 + 1] = b1;
                bm[(size_t)ch * 4 + 2] = b2;
                bm[(size_t)ch * 4 + 3] = b3;
            }
        }
        return;
    }

    // ---- proj role ----
    const int tid = threadIdx.x;
    const int w = tid >> 6, ln = tid & 63, qd = ln >> 4, l16 = ln & 15;
    const int row0 = blockIdx.x * 64;
    const int rw = row0 + w * 16;
    const int b = row0 >> 10, n0 = row0 & 1023;

    f16x8 xa[4];
    {
        const float* xr = x + (size_t)(rw + l16) * 128;
        #pragma unroll
        for (int t = 0; t < 4; ++t) {
            f32x4 a0 = *(const f32x4*)(xr + t * 32 + qd * 8);
            f32x4 a1 = *(const f32x4*)(xr + t * 32 + qd * 8 + 4);
            #pragma unroll
            for (int j = 0; j < 4; ++j) { xa[t][j] = (_Float16)a0[j]; xa[t][4 + j] = (_Float16)a1[j]; }
        }
    }

    for (int p = 0; p < 3; ++p) {
        const _Float16* Wt = g_WT + p * 16384;
        const float* bias = (p == 0) ? bq : (p == 1) ? bk : bv;

        float bv_[8];
        #pragma unroll
        for (int hc = 0; hc < 8; ++hc) bv_[hc] = bias[hc * 16 + l16];

        f32x4 acc[8];
        #pragma unroll
        for (int hc = 0; hc < 8; ++hc) {
            acc[hc] = (f32x4)(0.0f);
            #pragma unroll
            for (int t = 0; t < 4; ++t) {
                f16x8 bf = *(const f16x8*)(Wt + (size_t)(hc * 16 + l16) * 128 + t * 32 + qd * 8);
                acc[hc] = __builtin_amdgcn_mfma_f32_16x16x32_f16(xa[t], bf, acc[hc], 0, 0, 0);
            }
        }

        if (p < 2) {
            _Float16* dst = (p == 0) ? qo : ko;
            const float scl = (p == 0) ? LOG2E : 1.0f;   // fold exp2 domain into q
            #pragma unroll
            for (int hc = 0; hc < 8; ++hc)
                #pragma unroll
                for (int r = 0; r < 4; ++r)
                    rep[w][(qd * 4 + r) * 136 + hc * 16 + l16] =
                        (_Float16)(fmaxf(acc[hc][r] + bv_[hc], 0.0f) * scl);
            #pragma unroll
            for (int s = 0; s < 4; ++s) {
                int ch = ln + s * 64;
                int rr = ch >> 4, kc = ch & 15;
                f16x8 v = *(const f16x8*)&rep[w][rr * 136 + kc * 8];
                *(f16x8*)&dst[(size_t)(rw + rr) * 128 + kc * 8] = v;
            }
        } else {
            #pragma unroll
            for (int hc = 0; hc < 8; ++hc)
                #pragma unroll
                for (int r = 0; r < 4; ++r)
                    vsm[(hc * 16 + l16) * 72 + w * 16 + qd * 4 + r] =
                        f2bf(fmaxf(acc[hc][r] + bv_[hc], 0.0f));
            __syncthreads();
            #pragma unroll
            for (int s = 0; s < 4; ++s) {
                int ch = tid + s * 256;
                int h = ch >> 3, g = ch & 7;
                u16x8 v = *(const u16x8*)&vsm[h * 72 + g * 8];
                *(u16x8*)&vTo[(size_t)b * HH * NN + (size_t)h * NN + n0 + g * 8] = v;
            }
        }
    }
}

// ---------------- Fused attention: DMA-staged, S^T, no-max softmax -----------
// grid 512: b = id&31 (XCD pin), ig = id>>5; 64 i-rows, 512 thr = 8 waves.
// q arrives pre-scaled by log2e -> p = exp2(s) directly, UNNORMALIZED:
// no running max, no rescale, no loop-carried dependency (scores bounded ~25;
// p <= ~1e11 fits fp32/bf16; P + V are bf16 for range). l is per-lane, reduced
// once at the end; merge = (accA+accB)/(lA+lB).
__global__ __launch_bounds__(512, 4) void attn_kernel(
    const _Float16* __restrict__ q, const _Float16* __restrict__ k,
    const ushort* __restrict__ vT, const u64* __restrict__ bm,
    float* __restrict__ out)
{
    __shared__ __align__(16) unsigned char smem[43008];
    _Float16* ks = (_Float16*)smem;                  // [2 halves][8192 B] swizzled
    ushort* vs = (ushort*)(smem + 16384);            // [2 halves][8192 B] swizzled
    ushort* ps = (ushort*)(smem + 32768);            // [8 waves][16*40] bf16
    float* mg = (float*)smem;                        // merge overlay after loop

    const int tid = threadIdx.x;
    const int w = tid >> 6, ln = tid & 63, qd = ln >> 4, l16 = ln & 15;
    const int pair = w >> 1, half = w & 1;
    const int b = blockIdx.x & 31, ig = blockIdx.x >> 5;
    const int i0 = ig * 64 + pair * 16;

    ushort* psw = ps + w * 640;

    // Q B-fragments (n = l16 = i, k = qd*8+j)
    f16x8 qf[4];
    {
        const _Float16* qrow = q + ((size_t)b * NN + i0 + l16) * 128;
        #pragma unroll
        for (int t = 0; t < 4; ++t)
            qf[t] = *(const f16x8*)(qrow + t * 32 + qd * 8);
    }

    f32x4 acc[8];
    #pragma unroll
    for (int hc = 0; hc < 8; ++hc) acc[hc] = (f32x4)(0.0f);
    float l_i = 0.0f;

    u64 mw[4];
    const u64* mwp = bm + ((size_t)b * NN + i0 + l16) * 16;

    for (int jt = 0; jt < 16; ++jt) {
        __syncthreads();                      // previous compute done with LDS
        // ---- stage tile jt via DMA: waves 0-3 K, waves 4-7 V; 4x1KB each ----
        if (w < 4) {
            const int kh = w >> 1, gb = (w & 1) * 4;
            const _Float16* kg = k + ((size_t)b * NN + kh * 512 + jt * 32) * 128;
            unsigned char* ldsb = smem + kh * 8192;
            #pragma unroll
            for (int gi = 0; gi < 4; ++gi) {
                int g  = gb + gi;
                int r  = g * 4 + (ln >> 4);
                int cs = (ln & 15) ^ (r & 15);
                __builtin_amdgcn_global_load_lds(
                    (const AS1 void*)(kg + (size_t)r * 128 + cs * 8),
                    (AS3 void*)(ldsb + g * 1024 + (ln & 15) * 16),
                    16, 0, 0);
            }
        } else {
            const int vw = w - 4;
            const int vh = vw >> 1, gb = (vw & 1) * 4;
            const ushort* vg = vT + (size_t)b * HH * NN + vh * 512 + jt * 32;
            unsigned char* ldsb = smem + 16384 + vh * 8192;
            #pragma unroll
            for (int gi = 0; gi < 4; ++gi) {
                int g  = gb + gi;
                int h  = g * 16 + (ln >> 2);
                int cs = (ln & 3) ^ (h & 3);
                __builtin_amdgcn_global_load_lds(
                    (const AS1 void*)(vg + (size_t)h * NN + cs * 8),
                    (AS3 void*)(ldsb + g * 1024 + (ln & 3) * 16),
                    16, 0, 0);
            }
        }
        // mask words: once per 8 tiles (4 u64 = bits for 256 j)
        if ((jt & 7) == 0) {
            const u64* mp = mwp + (half * 2 + (jt >> 3)) * 4;
            mw[0] = mp[0]; mw[1] = mp[1]; mw[2] = mp[2]; mw[3] = mp[3];
        }
        __syncthreads();                      // DMA complete (vmcnt drain)

        // ---- compute ----
        const _Float16* ksh = ks + half * 4096;   // f16 units
        const ushort* vsh = vs + half * 4096;

        f32x4 s0 = (f32x4)(0.0f), s1 = (f32x4)(0.0f);
        #pragma unroll
        for (int t = 0; t < 4; ++t) {
            f16x8 kc = *(const f16x8*)&ksh[l16 * 128 + (((t * 4 + qd) ^ l16) * 8)];
            s0 = __builtin_amdgcn_mfma_f32_16x16x32_f16(kc, qf[t], s0, 0, 0, 0);
        }
        #pragma unroll
        for (int t = 0; t < 4; ++t) {
            f16x8 kc = *(const f16x8*)&ksh[(16 + l16) * 128 + (((t * 4 + qd) ^ l16) * 8)];
            s1 = __builtin_amdgcn_mfma_f32_16x16x32_f16(kc, qf[t], s1, 0, 0, 0);
        }

        // no-max softmax: p = exp2(s) (q pre-scaled by log2e), masked -> 0
        const int sh0 = (jt & 7) * 8 + qd, sh1 = sh0 + 4;
        float p[8], rs = 0.0f;
        #pragma unroll
        for (int r = 0; r < 4; ++r) {
            float lg0 = ((mw[r] >> sh0) & 1ull) ? s0[r] : -__builtin_inff();
            float lg1 = ((mw[r] >> sh1) & 1ull) ? s1[r] : -__builtin_inff();
            p[r]     = exp2f(lg0);
            p[4 + r] = exp2f(lg1);
        }
        #pragma unroll
        for (int z = 0; z < 8; ++z) rs += p[z];
        l_i += rs;

        // P -> LDS as bf16 (wave-private; stride 40)
        u16x4 pk0, pk1;
        #pragma unroll
        for (int r = 0; r < 4; ++r) { pk0[r] = f2bf(p[r]); pk1[r] = f2bf(p[4 + r]); }
        *(u16x4*)&psw[l16 * 40 + qd * 4]      = pk0;
        *(u16x4*)&psw[l16 * 40 + 16 + qd * 4] = pk1;

        s16x8 pb = *(const s16x8*)&psw[l16 * 40 + qd * 8];
        #pragma unroll
        for (int hc = 0; hc < 8; ++hc) {
            s16x8 vf = *(const s16x8*)&vsh[(hc * 16 + l16) * 32 + ((qd ^ (l16 & 3)) * 8)];
            acc[hc] = __builtin_amdgcn_mfma_f32_16x16x32_bf16(vf, pb, acc[hc], 0, 0, 0);
        }
    }

    // reduce l across quads (j-partition within half)
    l_i += __shfl_xor(l_i, 16);
    l_i += __shfl_xor(l_i, 32);

    // ---- merge the two j-halves (overlay on smem) ----
    __syncthreads();
    float* mgp = mg + pair * 2176;          // [16 i][136] per pair (4 pairs)
    float* ml  = mg + 8704;                 // [pair][16] l only
    if (half == 1) {
        #pragma unroll
        for (int hc = 0; hc < 8; ++hc)
            *(f32x4*)&mgp[l16 * 136 + hc * 16 + qd * 4] = acc[hc];
        if (qd == 0) ml[pair * 16 + l16] = l_i;
    }
    __syncthreads();
    if (half == 0) {
        float inv = 1.0f / (l_i + ml[pair * 16 + l16]);
        float* orow = out + ((size_t)b * NN + i0 + l16) * 128;
        #pragma unroll
        for (int hc = 0; hc < 8; ++hc) {
            f32x4 o1 = *(const f32x4*)&mgp[l16 * 136 + hc * 16 + qd * 4];
            f32x4 o = (acc[hc] + o1) * inv;
            *(f32x4*)&orow[hc * 16 + qd * 4] = o;
        }
    }
}

extern "C" void kernel_launch(void* const* d_in, const int* in_sizes, int n_in,
                              void* d_out, int out_size, void* d_ws, size_t ws_size,
                              hipStream_t stream) {
    const float* x    = (const float*)d_in[0];
    const float* mask = (const float*)d_in[1];
    const float* Wv   = (const float*)d_in[2];
    const float* bv   = (const float*)d_in[3];
    const float* Wk   = (const float*)d_in[4];
    const float* bk   = (const float*)d_in[5];
    const float* Wq   = (const float*)d_in[6];
    const float* bq   = (const float*)d_in[7];
    float* out = (float*)d_out;

    const size_t BNH = (size_t)BB * NN * HH;
    _Float16* ws  = (_Float16*)d_ws;
    ushort*   vTb = (ushort*)ws;              // [B][H][N] bf16   8 MB
    _Float16* kb  = ws + BNH;                 // [B][N][H] f16    8 MB
    _Float16* qb  = ws + 2 * BNH;             // [B][N][H] f16    8 MB
    u64* bm64 = (u64*)(ws + 3 * BNH);         // 4 MB bit words

    wtrans_kernel<<<3, 256, 0, stream>>>(Wq, Wk, Wv);
    prep_kernel<<<1536, 256, 0, stream>>>(x, bq, bk, bv, mask, qb, kb, vTb, bm64);
    attn_kernel<<<512, 512, 0, stream>>>(qb, kb, vTb, bm64, out);
}

// Round 10
// 268.733 us; speedup vs baseline: 1.4664x; 1.0065x over previous
//
#include <hip/hip_runtime.h>
#include <hip/hip_bf16.h>
#include <stddef.h>

#define BB 32
#define NN 1024
#define HH 128

using f32x4 = __attribute__((ext_vector_type(4))) float;
using f16x8 = __attribute__((ext_vector_type(8))) _Float16;
using f16x4 = __attribute__((ext_vector_type(4))) _Float16;
using s16x8 = __attribute__((ext_vector_type(8))) short;
using u16x4 = __attribute__((ext_vector_type(4))) unsigned short;
using u16x8 = __attribute__((ext_vector_type(8))) unsigned short;
typedef unsigned long long u64;
typedef unsigned short ushort;

#define AS1 __attribute__((address_space(1)))
#define AS3 __attribute__((address_space(3)))
#define LOG2E 1.44269504f

static __device__ inline ushort f2bf(float f) {
    __hip_bfloat16 h = __float2bfloat16(f);   // RNE
    return __builtin_bit_cast(ushort, h);
}

// W^T in fp16, [p][n][k] = W_p[k][n]; p: 0=q, 1=k, 2=v.
__device__ _Float16 g_WT[3 * 128 * 128];

// ---------------- W transpose + cast to fp16 (3 blocks; LDS padded to 129) ----
__global__ __launch_bounds__(256) void wtrans_kernel(const float* __restrict__ Wq,
                                                     const float* __restrict__ Wk,
                                                     const float* __restrict__ Wv) {
    __shared__ float wl[128 * 129];
    const float* W = (blockIdx.x == 0) ? Wq : (blockIdx.x == 1) ? Wk : Wv;
    _Float16* dst = g_WT + blockIdx.x * 16384;
    const int tid = threadIdx.x;
    for (int i = tid; i < 4096; i += 256) {
        int row = i >> 5, c = i & 31;
        *(f32x4*)&wl[row * 129 + c * 4] = ((const f32x4*)W)[i];
    }
    __syncthreads();
    for (int s = 0; s < 8; ++s) {
        int ch = tid + s * 256;
        int n = ch >> 4, kc = ch & 15;
        f16x8 v;
        #pragma unroll
        for (int j = 0; j < 8; ++j) v[j] = (_Float16)wl[(kc * 8 + j) * 129 + n];
        *(f16x8*)&dst[n * 128 + kc * 8] = v;
    }
}

// ---------------- Fused prep: proj (blocks 0-511) + maskpack (512-1535) ------
__global__ __launch_bounds__(256) void prep_kernel(
    const float* __restrict__ x,
    const float* __restrict__ bq, const float* __restrict__ bk, const float* __restrict__ bv,
    const float* __restrict__ mask,
    _Float16* __restrict__ qo, _Float16* __restrict__ ko, ushort* __restrict__ vTo,
    u64* __restrict__ bm)
{
    __shared__ __align__(16) _Float16 rep[4][16 * 136];
    __shared__ __align__(16) ushort vsm[128 * 72];

    if (blockIdx.x >= 512) {
        // ---- maskpack role: sequential stream, ballot pack ----
        const int wid = ((blockIdx.x - 512) * 256 + threadIdx.x) >> 6;
        const int ln = threadIdx.x & 63;
        for (int ch = wid; ch < BB * NN * NN / 256; ch += 4096) {
            f32x4 f = *(const f32x4*)(mask + (size_t)ch * 256 + ln * 4);
            u64 b0 = __ballot(f[0] != 0.0f);
            u64 b1 = __ballot(f[1] != 0.0f);
            u64 b2 = __ballot(f[2] != 0.0f);
            u64 b3 = __ballot(f[3] != 0.0f);
            if (ln == 0) {
                bm[(size_t)ch * 4 + 0] = b0;
                bm[(size_t)ch * 4 + 1] = b1;
                bm[(size_t)ch * 4 + 2] = b2;
                bm[(size_t)ch * 4 + 3] = b3;
            }
        }
        return;
    }

    // ---- proj role ----
    const int tid = threadIdx.x;
    const int w = tid >> 6, ln = tid & 63, qd = ln >> 4, l16 = ln & 15;
    const int row0 = blockIdx.x * 64;
    const int rw = row0 + w * 16;
    const int b = row0 >> 10, n0 = row0 & 1023;

    f16x8 xa[4];
    {
        const float* xr = x + (size_t)(rw + l16) * 128;
        #pragma unroll
        for (int t = 0; t < 4; ++t) {
            f32x4 a0 = *(const f32x4*)(xr + t * 32 + qd * 8);
            f32x4 a1 = *(const f32x4*)(xr + t * 32 + qd * 8 + 4);
            #pragma unroll
            for (int j = 0; j < 4; ++j) { xa[t][j] = (_Float16)a0[j]; xa[t][4 + j] = (_Float16)a1[j]; }
        }
    }

    for (int p = 0; p < 3; ++p) {
        const _Float16* Wt = g_WT + p * 16384;
        const float* bias = (p == 0) ? bq : (p == 1) ? bk : bv;

        float bv_[8];
        #pragma unroll
        for (int hc = 0; hc < 8; ++hc) bv_[hc] = bias[hc * 16 + l16];

        f32x4 acc[8];
        #pragma unroll
        for (int hc = 0; hc < 8; ++hc) {
            acc[hc] = (f32x4)(0.0f);
            #pragma unroll
            for (int t = 0; t < 4; ++t) {
                f16x8 bf = *(const f16x8*)(Wt + (size_t)(hc * 16 + l16) * 128 + t * 32 + qd * 8);
                acc[hc] = __builtin_amdgcn_mfma_f32_16x16x32_f16(xa[t], bf, acc[hc], 0, 0, 0);
            }
        }

        if (p < 2) {
            _Float16* dst = (p == 0) ? qo : ko;
            const float scl = (p == 0) ? LOG2E : 1.0f;   // fold exp2 domain into q
            #pragma unroll
            for (int hc = 0; hc < 8; ++hc)
                #pragma unroll
                for (int r = 0; r < 4; ++r)
                    rep[w][(qd * 4 + r) * 136 + hc * 16 + l16] =
                        (_Float16)(fmaxf(acc[hc][r] + bv_[hc], 0.0f) * scl);
            #pragma unroll
            for (int s = 0; s < 4; ++s) {
                int ch = ln + s * 64;
                int rr = ch >> 4, kc = ch & 15;
                f16x8 v = *(const f16x8*)&rep[w][rr * 136 + kc * 8];
                *(f16x8*)&dst[(size_t)(rw + rr) * 128 + kc * 8] = v;
            }
        } else {
            #pragma unroll
            for (int hc = 0; hc < 8; ++hc)
                #pragma unroll
                for (int r = 0; r < 4; ++r)
                    vsm[(hc * 16 + l16) * 72 + w * 16 + qd * 4 + r] =
                        f2bf(fmaxf(acc[hc][r] + bv_[hc], 0.0f));
            __syncthreads();
            #pragma unroll
            for (int s = 0; s < 4; ++s) {
                int ch = tid + s * 256;
                int h = ch >> 3, g = ch & 7;
                u16x8 v = *(const u16x8*)&vsm[h * 72 + g * 8];
                *(u16x8*)&vTo[(size_t)b * HH * NN + (size_t)h * NN + n0 + g * 8] = v;
            }
        }
    }
}

// ---------------- Fused attention: DOUBLE-BUFFERED DMA, S^T, no-max ----------
// grid 512: b = id&31 (XCD pin), ig = id>>5; 64 i-rows, 512 thr = 8 waves.
// ONE barrier per j-tile: iter jt issues DMA for tile jt+1 into buf^1, computes
// on buf (staged last iter), then __syncthreads (orders LDS reuse AND drains
// the in-flight DMA via its implicit vmcnt(0)). DMA latency hides behind
// MFMA+softmax instead of serializing. Mask-word loads are issued BEFORE the
// DMA batch so their wait (in-order vmcnt) doesn't drain the staging queue.
// LDS: K 2x16KB + V 2x16KB + ps 10KB = 74KB -> 2 blocks/CU (grid = 2/CU).
__global__ __launch_bounds__(512, 4) void attn_kernel(
    const _Float16* __restrict__ q, const _Float16* __restrict__ k,
    const ushort* __restrict__ vT, const u64* __restrict__ bm,
    float* __restrict__ out)
{
    __shared__ __align__(16) unsigned char smem[75776];
    // ks: buf*16384 + half*8192        (0 .. 32767)
    // vs: 32768 + buf*16384 + half*8192 (32768 .. 65535)
    // ps: 65536 + w*1280                (65536 .. 75775)
    float* mg = (float*)smem;                        // merge overlay after loop

    const int tid = threadIdx.x;
    const int w = tid >> 6, ln = tid & 63, qd = ln >> 4, l16 = ln & 15;
    const int pair = w >> 1, half = w & 1;
    const int b = blockIdx.x & 31, ig = blockIdx.x >> 5;
    const int i0 = ig * 64 + pair * 16;

    ushort* psw = (ushort*)(smem + 65536) + w * 640;

    // staging-role constants
    const int kh = (w & 3) >> 1, gb = (w & 1) * 4;   // K-half / group-base (w<4)
    const int vh = kh;                                // V-half (w>=4)
    const _Float16* kg0 = k + ((size_t)b * NN + kh * 512) * 128;
    const ushort*   vg0 = vT + (size_t)b * HH * NN + vh * 512;

    // Q B-fragments (n = l16 = i, k = qd*8+j)
    f16x8 qf[4];
    {
        const _Float16* qrow = q + ((size_t)b * NN + i0 + l16) * 128;
        #pragma unroll
        for (int t = 0; t < 4; ++t)
            qf[t] = *(const f16x8*)(qrow + t * 32 + qd * 8);
    }

    f32x4 acc[8];
    #pragma unroll
    for (int hc = 0; hc < 8; ++hc) acc[hc] = (f32x4)(0.0f);
    float l_i = 0.0f;

    u64 mw[4];
    const u64* mwp = bm + ((size_t)b * NN + i0 + l16) * 16;

    // ---- preload tile 0 into buf 0 ----
    if (w < 4) {
        unsigned char* ldsb = smem + kh * 8192;
        #pragma unroll
        for (int gi = 0; gi < 4; ++gi) {
            int g  = gb + gi;
            int r  = g * 4 + (ln >> 4);
            int cs = (ln & 15) ^ (r & 15);
            __builtin_amdgcn_global_load_lds(
                (const AS1 void*)(kg0 + (size_t)r * 128 + cs * 8),
                (AS3 void*)(ldsb + g * 1024 + (ln & 15) * 16),
                16, 0, 0);
        }
    } else {
        unsigned char* ldsb = smem + 32768 + vh * 8192;
        #pragma unroll
        for (int gi = 0; gi < 4; ++gi) {
            int g  = gb + gi;
            int h  = g * 16 + (ln >> 2);
            int cs = (ln & 3) ^ (h & 3);
            __builtin_amdgcn_global_load_lds(
                (const AS1 void*)(vg0 + (size_t)h * NN + cs * 8),
                (AS3 void*)(ldsb + g * 1024 + (ln & 3) * 16),
                16, 0, 0);
        }
    }
    __syncthreads();                           // tile 0 staged

    for (int jt = 0; jt < 16; ++jt) {
        const int cb = jt & 1, nb = cb ^ 1;

        // mask words first (their wait retires before the DMA batch, no drain)
        if ((jt & 7) == 0) {
            const u64* mp = mwp + (half * 2 + (jt >> 3)) * 4;
            mw[0] = mp[0]; mw[1] = mp[1]; mw[2] = mp[2]; mw[3] = mp[3];
        }

        // ---- issue DMA for tile jt+1 into nb (completes by next barrier) ----
        if (jt < 15) {
            const int jo = (jt + 1) * 32;
            if (w < 4) {
                unsigned char* ldsb = smem + nb * 16384 + kh * 8192;
                #pragma unroll
                for (int gi = 0; gi < 4; ++gi) {
                    int g  = gb + gi;
                    int r  = g * 4 + (ln >> 4);
                    int cs = (ln & 15) ^ (r & 15);
                    __builtin_amdgcn_global_load_lds(
                        (const AS1 void*)(kg0 + (size_t)(jo + r) * 128 + cs * 8),
                        (AS3 void*)(ldsb + g * 1024 + (ln & 15) * 16),
                        16, 0, 0);
                }
            } else {
                unsigned char* ldsb = smem + 32768 + nb * 16384 + vh * 8192;
                #pragma unroll
                for (int gi = 0; gi < 4; ++gi) {
                    int g  = gb + gi;
                    int h  = g * 16 + (ln >> 2);
                    int cs = (ln & 3) ^ (h & 3);
                    __builtin_amdgcn_global_load_lds(
                        (const AS1 void*)(vg0 + (size_t)h * NN + jo + cs * 8),
                        (AS3 void*)(ldsb + g * 1024 + (ln & 3) * 16),
                        16, 0, 0);
                }
            }
        }

        // ---- compute on cb ----
        const _Float16* ksh = (const _Float16*)(smem + cb * 16384) + half * 4096;
        const ushort*   vsh = (const ushort*)(smem + 32768 + cb * 16384) + half * 4096;

        f32x4 s0 = (f32x4)(0.0f), s1 = (f32x4)(0.0f);
        #pragma unroll
        for (int t = 0; t < 4; ++t) {
            f16x8 kc = *(const f16x8*)&ksh[l16 * 128 + (((t * 4 + qd) ^ l16) * 8)];
            s0 = __builtin_amdgcn_mfma_f32_16x16x32_f16(kc, qf[t], s0, 0, 0, 0);
        }
        #pragma unroll
        for (int t = 0; t < 4; ++t) {
            f16x8 kc = *(const f16x8*)&ksh[(16 + l16) * 128 + (((t * 4 + qd) ^ l16) * 8)];
            s1 = __builtin_amdgcn_mfma_f32_16x16x32_f16(kc, qf[t], s1, 0, 0, 0);
        }

        // no-max softmax: p = exp2(s) (q pre-scaled by log2e), masked -> 0
        const int sh0 = (jt & 7) * 8 + qd, sh1 = sh0 + 4;
        float p[8], rs = 0.0f;
        #pragma unroll
        for (int r = 0; r < 4; ++r) {
            float lg0 = ((mw[r] >> sh0) & 1ull) ? s0[r] : -__builtin_inff();
            float lg1 = ((mw[r] >> sh1) & 1ull) ? s1[r] : -__builtin_inff();
            p[r]     = exp2f(lg0);
            p[4 + r] = exp2f(lg1);
        }
        #pragma unroll
        for (int z = 0; z < 8; ++z) rs += p[z];
        l_i += rs;

        // P -> LDS as bf16 (wave-private; stride 40)
        u16x4 pk0, pk1;
        #pragma unroll
        for (int r = 0; r < 4; ++r) { pk0[r] = f2bf(p[r]); pk1[r] = f2bf(p[4 + r]); }
        *(u16x4*)&psw[l16 * 40 + qd * 4]      = pk0;
        *(u16x4*)&psw[l16 * 40 + 16 + qd * 4] = pk1;

        s16x8 pb = *(const s16x8*)&psw[l16 * 40 + qd * 8];
        #pragma unroll
        for (int hc = 0; hc < 8; ++hc) {
            s16x8 vf = *(const s16x8*)&vsh[(hc * 16 + l16) * 32 + ((qd ^ (l16 & 3)) * 8)];
            acc[hc] = __builtin_amdgcn_mfma_f32_16x16x32_bf16(vf, pb, acc[hc], 0, 0, 0);
        }

        __syncthreads();   // cb reads done; nb DMA drained (implicit vmcnt(0))
    }

    // reduce l across quads (j-partition within half)
    l_i += __shfl_xor(l_i, 16);
    l_i += __shfl_xor(l_i, 32);

    // ---- merge the two j-halves (overlay on smem) ----
    float* mgp = mg + pair * 2176;          // [16 i][136] per pair (4 pairs)
    float* ml  = mg + 8704;                 // [pair][16] l only
    if (half == 1) {
        #pragma unroll
        for (int hc = 0; hc < 8; ++hc)
            *(f32x4*)&mgp[l16 * 136 + hc * 16 + qd * 4] = acc[hc];
        if (qd == 0) ml[pair * 16 + l16] = l_i;
    }
    __syncthreads();
    if (half == 0) {
        float inv = 1.0f / (l_i + ml[pair * 16 + l16]);
        float* orow = out + ((size_t)b * NN + i0 + l16) * 128;
        #pragma unroll
        for (int hc = 0; hc < 8; ++hc) {
            f32x4 o1 = *(const f32x4*)&mgp[l16 * 136 + hc * 16 + qd * 4];
            f32x4 o = (acc[hc] + o1) * inv;
            *(f32x4*)&orow[hc * 16 + qd * 4] = o;
        }
    }
}

extern "C" void kernel_launch(void* const* d_in, const int* in_sizes, int n_in,
                              void* d_out, int out_size, void* d_ws, size_t ws_size,
                              hipStream_t stream) {
    const float* x    = (const float*)d_in[0];
    const float* mask = (const float*)d_in[1];
    const float* Wv   = (const float*)d_in[2];
    const float* bv   = (const float*)d_in[3];
    const float* Wk   = (const float*)d_in[4];
    const float* bk   = (const float*)d_in[5];
    const float* Wq   = (const float*)d_in[6];
    const float* bq   = (const float*)d_in[7];
    float* out = (float*)d_out;

    const size_t BNH = (size_t)BB * NN * HH;
    _Float16* ws  = (_Float16*)d_ws;
    ushort*   vTb = (ushort*)ws;              // [B][H][N] bf16   8 MB
    _Float16* kb  = ws + BNH;                 // [B][N][H] f16    8 MB
    _Float16* qb  = ws + 2 * BNH;             // [B][N][H] f16    8 MB
    u64* bm64 = (u64*)(ws + 3 * BNH);         // 4 MB bit words

    wtrans_kernel<<<3, 256, 0, stream>>>(Wq, Wk, Wv);
    prep_kernel<<<1536, 256, 0, stream>>>(x, bq, bk, bv, mask, qb, kb, vTb, bm64);
    attn_kernel<<<512, 512, 0, stream>>>(qb, kb, vTb, bm64, out);
}